// Round 4
// baseline (417.371 us; speedup 1.0000x reference)
//
#include <hip/hip_runtime.h>
#include <math.h>
#include <limits.h>

#define TPB   256
#define TILE  1024          // items per block-tile (256 thr x 4 rounds)
#define RNDS  4
#define MAXT  2048
#define TPAD  64            // pad so unconditional reads past e stay in-bounds
#define MAXK  1024
#define MAXW  29            // max span width in this problem (W=30 -> w<=29)
#define BATCH 1024          // greedy candidates per round (4 per thread)

// ===========================================================================
// Kernel A: fused key-build + 4-pass LSD radix argsort (60 blocks, grid bars)
// ===========================================================================
struct SortSM {
  union {
    unsigned h[4 * 256];                  // P0: 4 pass histograms
    struct {
      unsigned wcnt[4][256];              // [wave][digit] (also scan scratch)
      unsigned runCnt[256];
      unsigned baseL[256];
    } pass;
  };
};

// Device-scope grid barrier. SAFE: grid (<=60 blocks) fully co-resident on
// 256 CUs. ctr[] zeroed by memset node each launch.
__device__ inline void gbar(unsigned* ctr, int idx, unsigned nblk) {
  __syncthreads();
  if (threadIdx.x == 0) {
    __threadfence();
    atomicAdd(&ctr[idx], 1u);
    while (atomicAdd(&ctr[idx], 0u) < nblk) { __builtin_amdgcn_s_sleep(8); }
    __threadfence();
  }
  __syncthreads();
}

__global__ void __launch_bounds__(TPB, 1) sort_kernel(
    const float* __restrict__ scores, const float* __restrict__ mask,
    int N, int nT, unsigned* ctr, unsigned* ghist, unsigned* tileCnt,
    unsigned* keysA, unsigned* keysB, int* idxA, int* idxB) {
  __shared__ SortSM s;
  const int tid = threadIdx.x;
  const int lane = tid & 63;
  const int wave = tid >> 6;

  // ---- P0: build keys + all 4 histograms in one read ----
  for (int j = tid; j < 1024; j += TPB) s.h[j] = 0;
  __syncthreads();
  {
    const int tile0 = blockIdx.x * TILE;
    for (int r = 0; r < RNDS; ++r) {
      int i = tile0 + r * 256 + tid;
      if (i < N) {
        float kf = scores[i] + logf(mask[i]);          // mask==1 -> +0 exact
        unsigned u = __float_as_uint(kf);
        u = (u & 0x80000000u) ? ~u : (u | 0x80000000u);
        u = ~u;                                        // descending order
        keysA[i] = u;
        atomicAdd(&s.h[(u & 255u)], 1u);
        atomicAdd(&s.h[256 + ((u >> 8) & 255u)], 1u);
        atomicAdd(&s.h[512 + ((u >> 16) & 255u)], 1u);
        atomicAdd(&s.h[768 + (u >> 24)], 1u);
      }
    }
    __syncthreads();
    for (int j = tid; j < 1024; j += TPB)
      if (s.h[j]) atomicAdd(&ghist[j], s.h[j]);
  }
  gbar(ctr, 0, nT);

  // ---- P1: blocks 0..3 scan digit bases in parallel (256 excl each) ----
  if (blockIdx.x < 4) {
    const int p = blockIdx.x;
    unsigned v = ghist[p * 256 + tid];
    unsigned* A = s.pass.wcnt[0];
    unsigned* B = s.pass.wcnt[1];
    A[tid] = v;
    __syncthreads();
    for (int off = 1; off < 256; off <<= 1) {
      B[tid] = A[tid] + ((tid >= off) ? A[tid - off] : 0u);
      __syncthreads();
      unsigned* t = A; A = B; B = t;
    }
    ghist[p * 256 + tid] = A[tid] - v;
  }
  gbar(ctr, 1, nT);

  // ---- 4 fused rank/scatter radix passes ----
  for (int p = 0; p < 4; ++p) {
    const unsigned* srck = (p & 1) ? keysB : keysA;
    const int*      srci = (p & 1) ? idxB : idxA;     // p==0: payload = i
    unsigned*       dstk = (p & 1) ? keysA : keysB;
    int*            dsti = (p & 1) ? idxA : idxB;
    const int shift = 8 * p;
    const int tile0 = blockIdx.x * TILE;

    s.pass.runCnt[tid] = 0;
    unsigned mykey[RNDS]; int mypay[RNDS]; unsigned mypos[RNDS]; bool myval[RNDS];
    #pragma unroll
    for (int r = 0; r < RNDS; ++r) {
      __syncthreads();
      s.pass.wcnt[0][tid] = 0; s.pass.wcnt[1][tid] = 0;
      s.pass.wcnt[2][tid] = 0; s.pass.wcnt[3][tid] = 0;
      __syncthreads();
      int i = tile0 + r * 256 + tid;
      bool v = (i < N);
      unsigned key = v ? srck[i] : 0u;
      int pay = v ? ((p == 0) ? i : srci[i]) : 0;
      unsigned d = (key >> shift) & 255u;
      unsigned long long mm = __ballot(v);     // stable rank within wave
      #pragma unroll
      for (int b = 0; b < 8; ++b) {
        unsigned long long bb = __ballot((d >> b) & 1u);
        mm &= ((d >> b) & 1u) ? bb : ~bb;
      }
      int rank = (int)__popcll(mm & ((1ull << lane) - 1ull));
      if (v && rank == 0) s.pass.wcnt[wave][d] = (unsigned)__popcll(mm);
      __syncthreads();
      unsigned run0 = s.pass.runCnt[tid];
      unsigned run = 0;
      #pragma unroll
      for (int w2 = 0; w2 < 4; ++w2) {
        unsigned c = s.pass.wcnt[w2][tid];
        s.pass.wcnt[w2][tid] = run0 + run;
        run += c;
      }
      s.pass.runCnt[tid] = run0 + run;
      __syncthreads();
      mykey[r] = key; mypay[r] = pay; myval[r] = v;
      mypos[r] = v ? (s.pass.wcnt[wave][d] + (unsigned)rank) : 0u;
    }
    __syncthreads();
    tileCnt[blockIdx.x * 256 + tid] = s.pass.runCnt[tid];
    gbar(ctr, 2 + 2 * p, nT);

    unsigned baseacc = ghist[p * 256 + tid];
    for (int t = 0; t < blockIdx.x; ++t)
      baseacc += tileCnt[t * 256 + tid];
    s.pass.baseL[tid] = baseacc;
    __syncthreads();
    #pragma unroll
    for (int r = 0; r < RNDS; ++r) {
      if (myval[r]) {
        unsigned d = (mykey[r] >> shift) & 255u;
        unsigned pos = s.pass.baseL[d] + mypos[r];
        dstk[pos] = mykey[r];
        dsti[pos] = mypay[r];
      }
    }
    if (p < 3) gbar(ctr, 3 + 2 * p, nT);
  }
  // final order in idxA (A->B->A->B->A)
}

// ===========================================================================
// Kernel B: batched-speculative greedy (1 block, 256 threads) + epilogue.
// v4: O(1) pre-check via candidate rejection bitmap R[start] (bit w = span
//     (s, s+w) crosses an accepted span). R updated in parallel at round end
//     from the round's accept list; authoritative tab/tabP kept for the
//     resolver's in-round (dirty) re-checks.
// ===========================================================================
__device__ inline bool precheck30(const unsigned* tabP, int cc, int cs, int ce) {
  if (cc < 0) return false;
  int w = ce - cs;
  bool crossed = false;
  #pragma unroll
  for (int off = 0; off <= MAXW; ++off) {
    unsigned tv = tabP[cs + off];
    crossed |= ((off >= 1) & (off <= w) & ((tv & 0xFFFFu) > (unsigned)(ce + 1)))
             | ((off < w) & ((tv >> 16) < (unsigned)cs));
  }
  for (int off = MAXW + 1; off <= w; ++off) {   // generic fallback (unused)
    unsigned tv = tabP[cs + off];
    crossed |= ((tv & 0xFFFFu) > (unsigned)(ce + 1));
    if (off < w) crossed |= ((tv >> 16) < (unsigned)cs);
  }
  return !crossed;
}

__global__ void __launch_bounds__(TPB, 1) greedy_kernel(
    const int2* __restrict__ spans2, const int* __restrict__ spans,
    const float* __restrict__ scores, const int* __restrict__ order,
    const int* __restrict__ tnum_p, const int* __restrict__ keep_p,
    float* __restrict__ out, int N) {
  __shared__ unsigned tabP[MAXT + TPAD];  // hi16 = e2s(enc), lo16 = s2e+1
  __shared__ int2 tab[MAXT + TPAD];       // authoritative: .x=s2e, .y=e2s
  __shared__ unsigned R[MAXT];            // rejection bitmap: bit w of R[s]
  __shared__ unsigned long long acc[MAXK];
  __shared__ unsigned racc_s[MAXK];       // accepted (s<<16|e), for R update
  __shared__ unsigned long long surv[BATCH];
  __shared__ unsigned long long Cmat[BATCH];   // in-group crossing rows
  __shared__ int wvs[16];                      // survivor counts [quarter][wave]
  __shared__ int gcnt;

  const int tid = threadIdx.x;
  const int lane = tid & 63;
  const int wave = tid >> 6;
  const int T  = tnum_p[0];
  const int k0 = keep_p[0];
  const int k  = (k0 < MAXK) ? k0 : MAXK;

  for (int t = tid; t < MAXT + TPAD; t += TPB) {
    tab[t] = make_int2(-1, INT_MAX);
    tabP[t] = 0xFFFF0000u;               // s2e+1 = 0, e2s_enc = 0xFFFF
    if (t < MAXT) R[t] = 0u;
  }
  if (tid == 0) gcnt = 0;
  __syncthreads();

  // Each thread owns candidates q*256+tid (q=0..3) of every round.
  // ids prefetched 2 rounds ahead, spans 1 round ahead. Static indexing only.
  int cc[4], cs[4], ce[4], nn[4];
  #pragma unroll
  for (int q = 0; q < 4; ++q) {
    cc[q] = -1; nn[q] = -1; cs[q] = 0; ce[q] = 0;
    int i0 = q * 256 + tid;
    if (i0 < N) cc[q] = order[i0];
    int i1 = BATCH + q * 256 + tid;
    if (i1 < N) nn[q] = order[i1];
    if (cc[q] >= 0) { int2 sp = spans2[cc[q]]; cs[q] = sp.x; ce[q] = sp.y; }
  }

  int cnt = 0;
  for (int c0 = 0; c0 < N && cnt < k; c0 += BATCH) {
    // ---- prefetch next-round spans + next-next-round ids ----
    int pc[4], ps[4], pe[4];
    #pragma unroll
    for (int q = 0; q < 4; ++q) {
      pc[q] = nn[q]; ps[q] = 0; pe[q] = 0;
      if (pc[q] >= 0) { int2 sp = spans2[pc[q]]; ps[q] = sp.x; pe[q] = sp.y; }
      int i2 = c0 + 2 * BATCH + q * 256 + tid;
      nn[q] = (i2 < N) ? order[i2] : -1;
    }

    // ---- O(1) pre-check: rejection bitmap (fresh as of end of last round) --
    bool ok[4];
    unsigned long long bal[4];
    #pragma unroll
    for (int q = 0; q < 4; ++q) {
      ok[q] = (cc[q] >= 0) && !((R[cs[q]] >> (unsigned)(ce[q] - cs[q])) & 1u);
      bal[q] = __ballot(ok[q]);
      if (lane == 0) wvs[q * 4 + wave] = (int)__popcll(bal[q]);
    }
    __syncthreads();
    int qtot0 = wvs[0]  + wvs[1]  + wvs[2]  + wvs[3];
    int qtot1 = wvs[4]  + wvs[5]  + wvs[6]  + wvs[7];
    int qtot2 = wvs[8]  + wvs[9]  + wvs[10] + wvs[11];
    int qtot3 = wvs[12] + wvs[13] + wvs[14] + wvs[15];
    int ns = qtot0 + qtot1 + qtot2 + qtot3;

    if (ns > 0) {              // uniform branch: all threads agree on ns
      // ---- order-preserving survivor compression -> LDS (1024-wide) ----
      int qbase[4] = {0, qtot0, qtot0 + qtot1, qtot0 + qtot1 + qtot2};
      #pragma unroll
      for (int q = 0; q < 4; ++q) {
        if (ok[q]) {
          int wb = qbase[q];
          for (int w2 = 0; w2 < wave; ++w2) wb += wvs[q * 4 + w2];
          int pos = wb + (int)__popcll(bal[q] & ((1ull << lane) - 1ull));
          surv[pos] = ((unsigned long long)(unsigned)cs[q] << 48)
                    | ((unsigned long long)(unsigned)ce[q] << 32)
                    | (unsigned)cc[q];
        }
      }
      __syncthreads();

      // ---- parallel in-group crossing-matrix precompute (table-independent) ----
      for (int v = tid; v < ns; v += TPB) {
        unsigned long long pk = surv[v];
        int gs = (int)(pk >> 48), ge = (int)((pk >> 32) & 0xFFFFu);
        int gbase = v & ~63;
        int m = ns - gbase; if (m > 64) m = 64;
        unsigned long long C = 0;
        for (int j = 0; j < m; ++j) {
          unsigned long long pj = surv[gbase + j];
          int sj = (int)(pj >> 48), ej = (int)((pj >> 32) & 0xFFFFu);
          bool cr = (gs < sj && sj <= ge && ej > ge) ||
                    (sj < gs && gs <= ej && ej < ge);
          C |= (unsigned long long)cr << j;
        }
        Cmat[v] = C;
      }
      __syncthreads();

      const int cntPrev = cnt;
      // ---- wave-0 resolution, 64 survivors at a time ----
      if (tid < 64) {
        bool dirty = false;    // any in-batch acceptance since pre-check?
        for (int g = 0; g < ns && cnt < k; g += 64) {
          int m = ns - g; if (m > 64) m = 64;
          bool act = lane < m;
          int gs = 0, ge = 0, gc = 0;
          unsigned long long C = 0;
          if (act) {
            unsigned long long pk = surv[g + lane];
            gs = (int)(pk >> 48);
            ge = (int)((pk >> 32) & 0xFFFFu);
            gc = (int)(unsigned)pk;
            C  = Cmat[g + lane];
          }
          bool pre = act;
          if (dirty) {         // re-check only when tables changed in-batch
            pre = act && precheck30(tabP, gc, gs, ge);
          }
          unsigned long long preB = __ballot(pre);
          if (preB == 0ull) continue;
          int np = (int)__popcll(preB);
          unsigned long long lower = (1ull << lane) - 1ull;
          unsigned long long accm;
          int cnt0g = cnt;
          if (np == 1) {                       // single-survivor fast path
            accm = preB;
            cnt += 1;
          } else {
            if (cnt + np <= k) {
              // bulk: accept all with no earlier *surviving* in-group crosser
              bool easy = pre && ((C & lower & preB) == 0ull);
              accm = __ballot(easy);
              unsigned long long rem = preB & ~accm;
              while (rem) {
                unsigned long long kmask = __ballot((C & accm & lower) != 0ull);
                int j = __ffsll((long long)rem) - 1;
                rem &= rem - 1;
                if (!((kmask >> j) & 1ull)) accm |= 1ull << j;
              }
              cnt += (int)__popcll(accm);
            } else {
              // k-cap mode: strict serial order incl. count limit
              accm = 0ull;
              unsigned long long rem = preB;
              while (rem && cnt < k) {
                unsigned long long kmask = __ballot((C & accm & lower) != 0ull);
                int j = __ffsll((long long)rem) - 1;
                rem &= rem - 1;
                if (!((kmask >> j) & 1ull)) { accm |= 1ull << j; cnt++; }
              }
            }
          }
          bool accme = ((accm >> lane) & 1ull) != 0ull;
          if (accme) {
            int rank = (int)__popcll(accm & lower);
            acc[cnt0g + rank] =
                ((unsigned long long)(unsigned)(gs * T + ge) << 32) | (unsigned)gc;
            racc_s[cnt0g + rank] = ((unsigned)gs << 16) | (unsigned)ge;
            atomicMax(&tab[gs].x, ge);
            atomicMin(&tab[ge].y, gs);
          }
          if (accme) {      // same-wave DS in-order: reads see all atomics
            int2 tv = tab[gs];
            tabP[gs] = ((unsigned)(tv.y > 65535 ? 65535 : tv.y) << 16)
                     | (unsigned)(tv.x + 1);
            int2 tv2 = tab[ge];
            tabP[ge] = ((unsigned)(tv2.y > 65535 ? 65535 : tv2.y) << 16)
                     | (unsigned)(tv2.x + 1);
          }
          if (accm) dirty = true;
        }
        if (lane == 0) gcnt = cnt;
      }
      __syncthreads();
      cnt = gcnt;

      // ---- parallel R-bitmap update from this round's accepts ----
      // accepted (as,ae) rejects: cond1 s in [as-29,as-1], w in [as-s, ae-1-s]
      //                           cond2 s in [as+1,ae],   w in [ae-s+1, min(29,T-1-s)]
      // width-0 accepts (as==ae) reject nothing.
      for (int a = cntPrev; a < cnt; ++a) {
        unsigned pr = racc_s[a];               // LDS broadcast
        int as = (int)(pr >> 16), ae = (int)(pr & 0xFFFFu);
        if (ae > as) {
          int s = (as - MAXW) + tid;           // 59 consecutive starts max
          if (s >= 0 && s <= ae && s != as) {
            unsigned m = 0u;
            if (s < as) {
              int l1 = as - s;
              int h1 = ae - 1 - s; if (h1 > MAXW) h1 = MAXW;
              if (h1 >= l1)
                m = ((1u << (h1 + 1)) - 1u) & ~((1u << l1) - 1u);
            } else {
              int l2 = ae - s + 1;
              int h2 = T - 1 - s; if (h2 > MAXW) h2 = MAXW;
              if (h2 >= l2)
                m = ((1u << (h2 + 1)) - 1u) & ~((1u << l2) - 1u);
            }
            if (m) atomicOr(&R[s], m);
          }
        }
      }
      __syncthreads();   // next round's pre-check reads R
    }

    #pragma unroll
    for (int q = 0; q < 4; ++q) { cc[q] = pc[q]; cs[q] = ps[q]; ce[q] = pe[q]; }
  }

  // ---- bitonic ascending sort of acc[0..cnt) by (s*T+e, cand) ----
  int M = 2;
  while (M < cnt) M <<= 1;
  for (int j = tid; j < M; j += TPB)
    if (j >= cnt) acc[j] = ~0ull;
  __syncthreads();
  for (int kk = 2; kk <= M; kk <<= 1) {
    for (int jj = kk >> 1; jj > 0; jj >>= 1) {
      for (int i3 = tid; i3 < M; i3 += TPB) {
        int ixj = i3 ^ jj;
        if (ixj > i3) {
          unsigned long long a = acc[i3], b = acc[ixj];
          bool up = ((i3 & kk) == 0);
          if ((a > b) == up) { acc[i3] = b; acc[ixj] = a; }
        }
      }
      __syncthreads();
    }
  }

  // ---- epilogue: scores | idx | spans | valid, all f32 ----
  for (int j = tid; j < k0; j += TPB) {
    if (j < cnt) {
      int cand = (int)(acc[j] & 0xFFFFFFFFu);
      out[j]                  = scores[cand];
      out[k0 + j]             = (float)cand;
      out[2 * k0 + 2 * j]     = (float)spans[2 * cand];
      out[2 * k0 + 2 * j + 1] = (float)spans[2 * cand + 1];
      out[4 * k0 + j]         = 1.0f;
    } else {
      out[j]                  = 0.0f;
      out[k0 + j]             = 0.0f;
      out[2 * k0 + 2 * j]     = 0.0f;
      out[2 * k0 + 2 * j + 1] = 0.0f;
      out[4 * k0 + j]         = 0.0f;
    }
  }
}

extern "C" void kernel_launch(void* const* d_in, const int* in_sizes, int n_in,
                              void* d_out, int out_size, void* d_ws, size_t ws_size,
                              hipStream_t stream) {
  const int*   spans  = (const int*)d_in[0];
  const float* scores = (const float*)d_in[1];
  const float* mask   = (const float*)d_in[2];
  const int*   tnum   = (const int*)d_in[3];
  const int*   keep   = (const int*)d_in[4];
  const int N = in_sizes[1];
  const int nT = (N + TILE - 1) / TILE;   // 60 for N=61440

  // ws: ctr[32] | ghist[4*256] | tileCnt[nT*256] | keysA | keysB | idxA | idxB
  unsigned* ctr     = (unsigned*)d_ws;
  unsigned* ghist   = ctr + 32;
  unsigned* tileCnt = ghist + 4 * 256;
  unsigned* keysA   = tileCnt + (size_t)nT * 256;
  unsigned* keysB   = keysA + N;
  int*      idxA    = (int*)(keysB + N);
  int*      idxB    = idxA + N;
  float*    out     = (float*)d_out;

  hipMemsetAsync(ctr, 0, (32 + 4 * 256) * sizeof(unsigned), stream);

  sort_kernel<<<nT, TPB, 0, stream>>>(scores, mask, N, nT, ctr, ghist,
                                      tileCnt, keysA, keysB, idxA, idxB);
  greedy_kernel<<<1, TPB, 0, stream>>>((const int2*)spans, spans, scores,
                                       idxA, tnum, keep, out, N);
}

// Round 6
// 306.036 us; speedup vs baseline: 1.3638x; 1.3638x over previous
//
#include <hip/hip_runtime.h>
#include <math.h>
#include <limits.h>

#define TPB   256
#define TILE  1024          // items per block-tile (256 thr x 4 rounds)
#define RNDS  4
#define MAXT  2048
#define TPAD  64            // pad so unconditional reads past e stay in-bounds
#define MAXK  1024
#define MAXW  29            // max span width in this problem (W=30 -> w<=29)
#define BATCH 1024          // greedy candidates per round (4 per thread)

// ===========================================================================
// Kernel A: fused key-build + 4-pass LSD radix argsort (60 blocks, grid bars)
// ===========================================================================
struct SortSM {
  union {
    unsigned h[4 * 256];                  // P0: 4 pass histograms
    struct {
      unsigned wcnt[4][256];              // [wave][digit] (also scan scratch)
      unsigned runCnt[256];
      unsigned baseL[256];
    } pass;
  };
};

// Device-scope grid barrier. SAFE: grid (<=60 blocks) fully co-resident on
// 256 CUs. ctr[] zeroed by memset node each launch.
// Poll via device-scope atomic LOAD (no RMW serialization at the coherence
// point); every 256 spins issue one RMW as a guaranteed-coherent fallback so
// the loop provably terminates even if the load path were served stale.
__device__ inline void gbar(unsigned* ctr, int idx, unsigned nblk) {
  __syncthreads();
  if (threadIdx.x == 0) {
    __threadfence();
    atomicAdd(&ctr[idx], 1u);
    int spin = 0;
    while (__hip_atomic_load(&ctr[idx], __ATOMIC_ACQUIRE,
                             __HIP_MEMORY_SCOPE_AGENT) < nblk) {
      __builtin_amdgcn_s_sleep(2);
      if ((++spin & 255) == 0) {
        if (atomicAdd(&ctr[idx], 0u) >= nblk) break;   // coherent fallback
      }
    }
    __threadfence();
  }
  __syncthreads();
}

__global__ void __launch_bounds__(TPB, 1) sort_kernel(
    const float* __restrict__ scores, const float* __restrict__ mask,
    int N, int nT, unsigned* ctr, unsigned* ghist, unsigned* tileCnt,
    unsigned* keysA, unsigned* keysB, int* idxA, int* idxB) {
  __shared__ SortSM s;
  __shared__ unsigned base4[4][256];      // per-block copy of scanned bases
  const int tid = threadIdx.x;
  const int lane = tid & 63;
  const int wave = tid >> 6;

  // ---- P0: build keys + all 4 histograms in one read ----
  for (int j = tid; j < 1024; j += TPB) s.h[j] = 0;
  __syncthreads();
  {
    const int tile0 = blockIdx.x * TILE;
    for (int r = 0; r < RNDS; ++r) {
      int i = tile0 + r * 256 + tid;
      if (i < N) {
        float kf = scores[i] + logf(mask[i]);          // mask==1 -> +0 exact
        unsigned u = __float_as_uint(kf);
        u = (u & 0x80000000u) ? ~u : (u | 0x80000000u);
        u = ~u;                                        // descending order
        keysA[i] = u;
        atomicAdd(&s.h[(u & 255u)], 1u);
        atomicAdd(&s.h[256 + ((u >> 8) & 255u)], 1u);
        atomicAdd(&s.h[512 + ((u >> 16) & 255u)], 1u);
        atomicAdd(&s.h[768 + (u >> 24)], 1u);
      }
    }
    __syncthreads();
    for (int j = tid; j < 1024; j += TPB)
      if (s.h[j]) atomicAdd(&ghist[j], s.h[j]);
  }
  gbar(ctr, 0, nT);

  // ---- every block scans all 4 digit histograms locally (no grid phase) ----
  for (int p = 0; p < 4; ++p) {
    unsigned v = ghist[p * 256 + tid];
    unsigned* A = s.pass.wcnt[0];
    unsigned* B = s.pass.wcnt[1];
    A[tid] = v;
    __syncthreads();
    for (int off = 1; off < 256; off <<= 1) {
      B[tid] = A[tid] + ((tid >= off) ? A[tid - off] : 0u);
      __syncthreads();
      unsigned* t = A; A = B; B = t;
    }
    base4[p][tid] = A[tid] - v;            // exclusive scan
    __syncthreads();
  }

  // ---- 4 fused rank/scatter radix passes ----
  for (int p = 0; p < 4; ++p) {
    const unsigned* srck = (p & 1) ? keysB : keysA;
    const int*      srci = (p & 1) ? idxB : idxA;     // p==0: payload = i
    unsigned*       dstk = (p & 1) ? keysA : keysB;
    int*            dsti = (p & 1) ? idxA : idxB;
    const int shift = 8 * p;
    const int tile0 = blockIdx.x * TILE;

    s.pass.runCnt[tid] = 0;
    unsigned mykey[RNDS]; int mypay[RNDS]; unsigned mypos[RNDS]; bool myval[RNDS];
    #pragma unroll
    for (int r = 0; r < RNDS; ++r) {
      __syncthreads();
      s.pass.wcnt[0][tid] = 0; s.pass.wcnt[1][tid] = 0;
      s.pass.wcnt[2][tid] = 0; s.pass.wcnt[3][tid] = 0;
      __syncthreads();
      int i = tile0 + r * 256 + tid;
      bool v = (i < N);
      unsigned key = v ? srck[i] : 0u;
      int pay = v ? ((p == 0) ? i : srci[i]) : 0;
      unsigned d = (key >> shift) & 255u;
      unsigned long long mm = __ballot(v);     // stable rank within wave
      #pragma unroll
      for (int b = 0; b < 8; ++b) {
        unsigned long long bb = __ballot((d >> b) & 1u);
        mm &= ((d >> b) & 1u) ? bb : ~bb;
      }
      int rank = (int)__popcll(mm & ((1ull << lane) - 1ull));
      if (v && rank == 0) s.pass.wcnt[wave][d] = (unsigned)__popcll(mm);
      __syncthreads();
      unsigned run0 = s.pass.runCnt[tid];
      unsigned run = 0;
      #pragma unroll
      for (int w2 = 0; w2 < 4; ++w2) {
        unsigned c = s.pass.wcnt[w2][tid];
        s.pass.wcnt[w2][tid] = run0 + run;
        run += c;
      }
      s.pass.runCnt[tid] = run0 + run;
      __syncthreads();
      mykey[r] = key; mypay[r] = pay; myval[r] = v;
      mypos[r] = v ? (s.pass.wcnt[wave][d] + (unsigned)rank) : 0u;
    }
    __syncthreads();
    tileCnt[blockIdx.x * 256 + tid] = s.pass.runCnt[tid];
    gbar(ctr, 1 + 2 * p, nT);

    unsigned baseacc = base4[p][tid];
    for (int t = 0; t < blockIdx.x; ++t)
      baseacc += tileCnt[t * 256 + tid];
    s.pass.baseL[tid] = baseacc;
    __syncthreads();
    #pragma unroll
    for (int r = 0; r < RNDS; ++r) {
      if (myval[r]) {
        unsigned d = (mykey[r] >> shift) & 255u;
        unsigned pos = s.pass.baseL[d] + mypos[r];
        dstk[pos] = mykey[r];
        dsti[pos] = mypay[r];
      }
    }
    if (p < 3) gbar(ctr, 2 + 2 * p, nT);
  }
  // final order in idxA (A->B->A->B->A)
}

// ===========================================================================
// Kernel B: batched-speculative greedy (1 block, 256 threads) + epilogue.
// v3 (reverted): 1024-candidate rounds (4/thread) + parallel crossing-matrix
// precompute + uniform empty-round skip.
// ===========================================================================
__device__ inline bool precheck(const unsigned* tabP, int cc, int cs, int ce) {
  if (cc < 0) return false;
  int w = ce - cs;
  bool crossed = false;
  #pragma unroll
  for (int off = 0; off <= MAXW; ++off) {
    unsigned tv = tabP[cs + off];
    crossed |= ((off >= 1) & (off <= w) & ((tv & 0xFFFFu) > (unsigned)(ce + 1)))
             | ((off < w) & ((tv >> 16) < (unsigned)cs));
  }
  for (int off = MAXW + 1; off <= w; ++off) {   // generic fallback (unused)
    unsigned tv = tabP[cs + off];
    crossed |= ((tv & 0xFFFFu) > (unsigned)(ce + 1));
    if (off < w) crossed |= ((tv >> 16) < (unsigned)cs);
  }
  return !crossed;
}

__global__ void __launch_bounds__(TPB, 1) greedy_kernel(
    const int2* __restrict__ spans2, const int* __restrict__ spans,
    const float* __restrict__ scores, const int* __restrict__ order,
    const int* __restrict__ tnum_p, const int* __restrict__ keep_p,
    float* __restrict__ out, int N) {
  __shared__ unsigned tabP[MAXT + TPAD];  // hi16 = e2s(enc), lo16 = s2e+1
  __shared__ int2 tab[MAXT + TPAD];       // authoritative: .x=s2e, .y=e2s
  __shared__ unsigned long long acc[MAXK];
  __shared__ unsigned long long surv[BATCH];
  __shared__ unsigned long long Cmat[BATCH];   // in-group crossing rows
  __shared__ int wvs[16];                      // survivor counts [quarter][wave]
  __shared__ int gcnt;

  const int tid = threadIdx.x;
  const int lane = tid & 63;
  const int wave = tid >> 6;
  const int T  = tnum_p[0];
  const int k0 = keep_p[0];
  const int k  = (k0 < MAXK) ? k0 : MAXK;

  for (int t = tid; t < MAXT + TPAD; t += TPB) {
    tab[t] = make_int2(-1, INT_MAX);
    tabP[t] = 0xFFFF0000u;               // s2e+1 = 0, e2s_enc = 0xFFFF
  }
  if (tid == 0) gcnt = 0;
  __syncthreads();

  // Each thread owns candidates q*256+tid (q=0..3) of every round.
  // ids prefetched 2 rounds ahead, spans 1 round ahead. Static indexing only.
  int cc[4], cs[4], ce[4], nn[4];
  #pragma unroll
  for (int q = 0; q < 4; ++q) {
    cc[q] = -1; nn[q] = -1; cs[q] = 0; ce[q] = 0;
    int i0 = q * 256 + tid;
    if (i0 < N) cc[q] = order[i0];
    int i1 = BATCH + q * 256 + tid;
    if (i1 < N) nn[q] = order[i1];
    if (cc[q] >= 0) { int2 sp = spans2[cc[q]]; cs[q] = sp.x; ce[q] = sp.y; }
  }

  int cnt = 0;
  for (int c0 = 0; c0 < N && cnt < k; c0 += BATCH) {
    // ---- prefetch next-round spans + next-next-round ids ----
    int pc[4], ps[4], pe[4];
    #pragma unroll
    for (int q = 0; q < 4; ++q) {
      pc[q] = nn[q]; ps[q] = 0; pe[q] = 0;
      if (pc[q] >= 0) { int2 sp = spans2[pc[q]]; ps[q] = sp.x; pe[q] = sp.y; }
      int i2 = c0 + 2 * BATCH + q * 256 + tid;
      nn[q] = (i2 < N) ? order[i2] : -1;
    }

    // ---- parallel pre-check vs packed tables (monotone -> speculative) ----
    bool ok[4];
    unsigned long long bal[4];
    #pragma unroll
    for (int q = 0; q < 4; ++q) {
      ok[q] = precheck(tabP, cc[q], cs[q], ce[q]);
      bal[q] = __ballot(ok[q]);
      if (lane == 0) wvs[q * 4 + wave] = (int)__popcll(bal[q]);
    }
    __syncthreads();
    int qtot0 = wvs[0]  + wvs[1]  + wvs[2]  + wvs[3];
    int qtot1 = wvs[4]  + wvs[5]  + wvs[6]  + wvs[7];
    int qtot2 = wvs[8]  + wvs[9]  + wvs[10] + wvs[11];
    int qtot3 = wvs[12] + wvs[13] + wvs[14] + wvs[15];
    int ns = qtot0 + qtot1 + qtot2 + qtot3;

    if (ns > 0) {              // uniform branch: all threads agree on ns
      // ---- order-preserving survivor compression -> LDS (1024-wide) ----
      int qbase[4] = {0, qtot0, qtot0 + qtot1, qtot0 + qtot1 + qtot2};
      #pragma unroll
      for (int q = 0; q < 4; ++q) {
        if (ok[q]) {
          int wb = qbase[q];
          for (int w2 = 0; w2 < wave; ++w2) wb += wvs[q * 4 + w2];
          int pos = wb + (int)__popcll(bal[q] & ((1ull << lane) - 1ull));
          surv[pos] = ((unsigned long long)(unsigned)cs[q] << 48)
                    | ((unsigned long long)(unsigned)ce[q] << 32)
                    | (unsigned)cc[q];
        }
      }
      __syncthreads();

      // ---- parallel in-group crossing-matrix precompute (table-independent) ----
      for (int v = tid; v < ns; v += TPB) {
        unsigned long long pk = surv[v];
        int gs = (int)(pk >> 48), ge = (int)((pk >> 32) & 0xFFFFu);
        int gbase = v & ~63;
        int m = ns - gbase; if (m > 64) m = 64;
        unsigned long long C = 0;
        for (int j = 0; j < m; ++j) {
          unsigned long long pj = surv[gbase + j];
          int sj = (int)(pj >> 48), ej = (int)((pj >> 32) & 0xFFFFu);
          bool cr = (gs < sj && sj <= ge && ej > ge) ||
                    (sj < gs && gs <= ej && ej < ge);
          C |= (unsigned long long)cr << j;
        }
        Cmat[v] = C;
      }
      __syncthreads();

      // ---- wave-0 resolution, 64 survivors at a time ----
      if (tid < 64) {
        bool dirty = false;    // any in-batch acceptance since pre-check?
        for (int g = 0; g < ns && cnt < k; g += 64) {
          int m = ns - g; if (m > 64) m = 64;
          bool act = lane < m;
          int gs = 0, ge = 0, gc = 0;
          unsigned long long C = 0;
          if (act) {
            unsigned long long pk = surv[g + lane];
            gs = (int)(pk >> 48);
            ge = (int)((pk >> 32) & 0xFFFFu);
            gc = (int)(unsigned)pk;
            C  = Cmat[g + lane];
          }
          bool pre = act;
          if (dirty) {         // re-check only when tables changed in-batch
            pre = act && precheck(tabP, gc, gs, ge);
          }
          unsigned long long preB = __ballot(pre);
          if (preB == 0ull) continue;
          int np = (int)__popcll(preB);
          unsigned long long lower = (1ull << lane) - 1ull;
          unsigned long long accm;
          int cnt0g = cnt;
          if (np == 1) {                       // single-survivor fast path
            accm = preB;
            cnt += 1;
          } else {
            if (cnt + np <= k) {
              // bulk: accept all with no earlier *surviving* in-group crosser
              bool easy = pre && ((C & lower & preB) == 0ull);
              accm = __ballot(easy);
              unsigned long long rem = preB & ~accm;
              while (rem) {
                unsigned long long kmask = __ballot((C & accm & lower) != 0ull);
                int j = __ffsll((long long)rem) - 1;
                rem &= rem - 1;
                if (!((kmask >> j) & 1ull)) accm |= 1ull << j;
              }
              cnt += (int)__popcll(accm);
            } else {
              // k-cap mode: strict serial order incl. count limit
              accm = 0ull;
              unsigned long long rem = preB;
              while (rem && cnt < k) {
                unsigned long long kmask = __ballot((C & accm & lower) != 0ull);
                int j = __ffsll((long long)rem) - 1;
                rem &= rem - 1;
                if (!((kmask >> j) & 1ull)) { accm |= 1ull << j; cnt++; }
              }
            }
          }
          bool accme = ((accm >> lane) & 1ull) != 0ull;
          if (accme) {
            int rank = (int)__popcll(accm & lower);
            acc[cnt0g + rank] =
                ((unsigned long long)(unsigned)(gs * T + ge) << 32) | (unsigned)gc;
            atomicMax(&tab[gs].x, ge);
            atomicMin(&tab[ge].y, gs);
          }
          if (accme) {      // same-wave DS in-order: reads see all atomics
            int2 tv = tab[gs];
            tabP[gs] = ((unsigned)(tv.y > 65535 ? 65535 : tv.y) << 16)
                     | (unsigned)(tv.x + 1);
            int2 tv2 = tab[ge];
            tabP[ge] = ((unsigned)(tv2.y > 65535 ? 65535 : tv2.y) << 16)
                     | (unsigned)(tv2.x + 1);
          }
          if (accm) dirty = true;
        }
        if (lane == 0) gcnt = cnt;
      }
      __syncthreads();
      cnt = gcnt;
    }

    #pragma unroll
    for (int q = 0; q < 4; ++q) { cc[q] = pc[q]; cs[q] = ps[q]; ce[q] = pe[q]; }
  }

  // ---- bitonic ascending sort of acc[0..cnt) by (s*T+e, cand) ----
  int M = 2;
  while (M < cnt) M <<= 1;
  for (int j = tid; j < M; j += TPB)
    if (j >= cnt) acc[j] = ~0ull;
  __syncthreads();
  for (int kk = 2; kk <= M; kk <<= 1) {
    for (int jj = kk >> 1; jj > 0; jj >>= 1) {
      for (int i3 = tid; i3 < M; i3 += TPB) {
        int ixj = i3 ^ jj;
        if (ixj > i3) {
          unsigned long long a = acc[i3], b = acc[ixj];
          bool up = ((i3 & kk) == 0);
          if ((a > b) == up) { acc[i3] = b; acc[ixj] = a; }
        }
      }
      __syncthreads();
    }
  }

  // ---- epilogue: scores | idx | spans | valid, all f32 ----
  for (int j = tid; j < k0; j += TPB) {
    if (j < cnt) {
      int cand = (int)(acc[j] & 0xFFFFFFFFu);
      out[j]                  = scores[cand];
      out[k0 + j]             = (float)cand;
      out[2 * k0 + 2 * j]     = (float)spans[2 * cand];
      out[2 * k0 + 2 * j + 1] = (float)spans[2 * cand + 1];
      out[4 * k0 + j]         = 1.0f;
    } else {
      out[j]                  = 0.0f;
      out[k0 + j]             = 0.0f;
      out[2 * k0 + 2 * j]     = 0.0f;
      out[2 * k0 + 2 * j + 1] = 0.0f;
      out[4 * k0 + j]         = 0.0f;
    }
  }
}

extern "C" void kernel_launch(void* const* d_in, const int* in_sizes, int n_in,
                              void* d_out, int out_size, void* d_ws, size_t ws_size,
                              hipStream_t stream) {
  const int*   spans  = (const int*)d_in[0];
  const float* scores = (const float*)d_in[1];
  const float* mask   = (const float*)d_in[2];
  const int*   tnum   = (const int*)d_in[3];
  const int*   keep   = (const int*)d_in[4];
  const int N = in_sizes[1];
  const int nT = (N + TILE - 1) / TILE;   // 60 for N=61440

  // ws: ctr[32] | ghist[4*256] | tileCnt[nT*256] | keysA | keysB | idxA | idxB
  unsigned* ctr     = (unsigned*)d_ws;
  unsigned* ghist   = ctr + 32;
  unsigned* tileCnt = ghist + 4 * 256;
  unsigned* keysA   = tileCnt + (size_t)nT * 256;
  unsigned* keysB   = keysA + N;
  int*      idxA    = (int*)(keysB + N);
  int*      idxB    = idxA + N;
  float*    out     = (float*)d_out;

  hipMemsetAsync(ctr, 0, (32 + 4 * 256) * sizeof(unsigned), stream);

  sort_kernel<<<nT, TPB, 0, stream>>>(scores, mask, N, nT, ctr, ghist,
                                      tileCnt, keysA, keysB, idxA, idxB);
  greedy_kernel<<<1, TPB, 0, stream>>>((const int2*)spans, spans, scores,
                                       idxA, tnum, keep, out, N);
}